// Round 19
// baseline (45.871 us; speedup 1.0000x reference)
//
#include <hip/hip_runtime.h>

#define NB    65536
#define NUM_T 200
#define SUB   2          // SUB=8/4/2 all measured absmax == 0.0078125 (bf16
                         // comparison floor); threshold 0.0372
#define SPLIT 112        // A-waves store steps [0,112); B-waves ff then [112,200)

// one RK4 substep on rescaled state (u = beta*S, I); 22 VALU ops
#define SUBSTEP()                                   \
    do {                                            \
        const float bSI1 = u * I;                   \
        const float u2 = fmaf(-cbA, bSI1, u);       \
        const float J1 = fmaf(-cgA, I, I);          \
        const float I2 = fmaf(h2, bSI1, J1);        \
        const float bSI2 = u2 * I2;                 \
        const float u3 = fmaf(-cbA, bSI2, u);       \
        const float J2 = fmaf(-cgA, I2, I);         \
        const float I3 = fmaf(h2, bSI2, J2);        \
        float wb = fmaf(2.0f, bSI2, bSI1);          \
        float wI = fmaf(2.0f, I2, I);               \
        const float bSI3 = u3 * I3;                 \
        const float u4 = fmaf(-cbB, bSI3, u);       \
        const float J3 = fmaf(-cgB, I3, I);         \
        const float I4 = fmaf(h, bSI3, J3);         \
        wb = fmaf(2.0f, bSI3, wb);                  \
        wI = fmaf(2.0f, I3, wI);                    \
        const float bSI4 = u4 * I4;                 \
        wb += bSI4;                                 \
        wI += I4;                                   \
        u = fmaf(-cbF, wb, u);                      \
        const float tt = fmaf(-cgF, wI, I);         \
        I = fmaf(h6, wb, tt);                       \
    } while (0)

// advance one output step (i>0), per-step dt from the fp32 linspace chain
#define STEP(iexpr)                                                     \
    do {                                                                \
        const float tcur = step * (float)(iexpr);                       \
        const float dt   = tcur - tprev;                                \
        tprev = tcur;                                                   \
        const float h  = dt * (1.0f / SUB);                             \
        const float h2 = 0.5f * h;                                      \
        const float h6 = h * (1.0f / 6.0f);                             \
        const float cbA = h2 * beta,  cbB = h * beta,  cbF = h6 * beta; \
        const float cgA = h2 * gamma, cgB = h * gamma, cgF = h6 * gamma;\
        for (int s = 0; s < SUB; ++s) SUBSTEP();                        \
    } while (0)

// compute 16 steps starting at BASE (compile-time), stage into own LDS row
#define EMIT16(BASE)                                                    \
    do {                                                                \
        _Pragma("unroll 1")                                             \
        for (int g = 0; g < 4; ++g) {                                   \
            float c[12];                                                \
            _Pragma("unroll")                                           \
            for (int j = 0; j < 4; ++j) {                               \
                const int i = (BASE) + g * 4 + j;                       \
                if (i > 0) STEP(i);                                     \
                const float Sout = bpos ? (u * rbeta) : S0;             \
                c[j * 3 + 0] = Sout;                                    \
                c[j * 3 + 1] = I;                                       \
                c[j * 3 + 2] = 1.0f - Sout - I;                         \
            }                                                           \
            _Pragma("unroll")                                           \
            for (int cc = 0; cc < 3; ++cc)                              \
                myrow[(g * 3 + cc) ^ key] =                             \
                    make_float4(c[cc*4], c[cc*4+1], c[cc*4+2], c[cc*4+3]); \
        }                                                               \
    } while (0)

// compute 8 steps (tail half-stage), 6 chunks
#define EMIT8(BASE)                                                     \
    do {                                                                \
        _Pragma("unroll 1")                                             \
        for (int g = 0; g < 2; ++g) {                                   \
            float c[12];                                                \
            _Pragma("unroll")                                           \
            for (int j = 0; j < 4; ++j) {                               \
                const int i = (BASE) + g * 4 + j;                       \
                STEP(i);                                                \
                const float Sout = bpos ? (u * rbeta) : S0;             \
                c[j * 3 + 0] = Sout;                                    \
                c[j * 3 + 1] = I;                                       \
                c[j * 3 + 2] = 1.0f - Sout - I;                         \
            }                                                           \
            _Pragma("unroll")                                           \
            for (int cc = 0; cc < 3; ++cc)                              \
                myrow[(g * 3 + cc) ^ key] =                             \
                    make_float4(c[cc*4], c[cc*4+1], c[cc*4+2], c[cc*4+3]); \
        }                                                               \
    } while (0)

#define LGKM0() asm volatile("s_waitcnt lgkmcnt(0)" ::: "memory")

// wave-local dense drain: NCH chunks/row, store at float4 offset SOFF
#define DRAIN(NCH, SOFF)                                                \
    do {                                                                \
        float4 dv[NCH];                                                 \
        _Pragma("unroll")                                               \
        for (int k = 0; k < (NCH); ++k) {                               \
            const int id = k * 64 + lane;                               \
            const int r  = id / (NCH);                                  \
            const int j  = id - r * (NCH);                              \
            dv[k] = ldsw[r * 16 + (j ^ (r & 7))];                       \
        }                                                               \
        _Pragma("unroll")                                               \
        for (int k = 0; k < (NCH); ++k) {                               \
            const int id = k * 64 + lane;                               \
            const int r  = id / (NCH);                                  \
            const int j  = id - r * (NCH);                              \
            out4[r * 150 + (SOFF) + j] = dv[k];                         \
        }                                                               \
    } while (0)

__global__ __launch_bounds__(512, 2) void sir_rk4_ab_kernel(
    const float4* __restrict__ params, float* __restrict__ out)
{
    // 8 wave-private slices x 64 rows x 16 float4 = 131072 B (1 block/CU)
    __shared__ float4 lds4[8 * 64 * 16];

    const int tid  = threadIdx.x;
    const int lane = tid & 63;
    const int wid  = tid >> 6;        // 0..7; SIMD s hosts wid s (A) + s+4 (B)
    const int seg  = tid >> 8;        // 0: steps [0,112)   1: steps [112,200)
    const int ws   = wid & 3;         // 64-system slice within segment
    const int blk  = blockIdx.x;
    const int key  = lane & 7;        // XOR bank swizzle

    const float4 p = params[blk * 256 + ws * 64 + lane];
    const float beta  = p.x;
    const float gamma = p.y;
    const float S0    = p.z;

    float u = beta * S0;              // rescaled state u = beta*S
    float I = p.w;

    const bool  bpos  = (beta > 0.0f);
    const float rbeta = bpos ? (1.0f / beta) : 0.0f;

    const float step = 100.0f / 199.0f;   // fp32 linspace step
    float tprev = 0.0f;

    float4* myrow = &lds4[wid * 1024 + lane * 16];
    const float4* ldsw = &lds4[wid * 1024];
    float4* out4 = reinterpret_cast<float4*>(out)
                 + (size_t)(blk * 256 + ws * 64) * 150
                 + (seg ? (SPLIT * 3 / 4) : 0);       // B rows offset 84 float4

    if (seg == 0) {
        // ---- A: 7 stages x 16 steps, steps 0..111 ----
        EMIT16(0);   LGKM0(); DRAIN(12, 0);
        EMIT16(16);  LGKM0(); DRAIN(12, 12);
        EMIT16(32);  LGKM0(); DRAIN(12, 24);
        EMIT16(48);  LGKM0(); DRAIN(12, 36);
        EMIT16(64);  LGKM0(); DRAIN(12, 48);
        EMIT16(80);  LGKM0(); DRAIN(12, 60);
        EMIT16(96);  LGKM0(); DRAIN(12, 72);
    } else {
        // ---- B: fast-forward steps 1..111 (pure VALU, hides A's stores) ----
        #pragma unroll 1
        for (int i = 1; i < SPLIT; ++i) {
            STEP(i);
        }
        // ---- then 5 stages + half-stage, steps 112..199 ----
        EMIT16(112); LGKM0(); DRAIN(12, 0);
        EMIT16(128); LGKM0(); DRAIN(12, 12);
        EMIT16(144); LGKM0(); DRAIN(12, 24);
        EMIT16(160); LGKM0(); DRAIN(12, 36);
        EMIT16(176); LGKM0(); DRAIN(12, 48);
        EMIT8(192);  LGKM0(); DRAIN(6, 60);
    }
}

extern "C" void kernel_launch(void* const* d_in, const int* in_sizes, int n_in,
                              void* d_out, int out_size, void* d_ws, size_t ws_size,
                              hipStream_t stream) {
    (void)in_sizes; (void)n_in; (void)out_size; (void)d_ws; (void)ws_size;
    const float4* params = (const float4*)d_in[0];
    float* out = (float*)d_out;
    // 2 threads per system (A/B time segments), 512-thread blocks = 1 block/CU
    sir_rk4_ab_kernel<<<NB / 256, 512, 0, stream>>>(params, out);
}

// Round 20
// 41.120 us; speedup vs baseline: 1.1155x; 1.1155x over previous
//
#include <hip/hip_runtime.h>

#define NB 65536
#define NUM_T 200
#define SUB 2            // SUB=8/4/2 all measured absmax == 0.0078125 (bf16
                         // comparison floor); threshold 0.0372

// one RK4 substep on rescaled state (u = beta*S, I); 22 VALU ops
#define SUBSTEP()                                   \
    do {                                            \
        const float bSI1 = u * I;                   \
        const float u2 = fmaf(-cbA, bSI1, u);       \
        const float J1 = fmaf(-cgA, I, I);          \
        const float I2 = fmaf(h2, bSI1, J1);        \
        const float bSI2 = u2 * I2;                 \
        const float u3 = fmaf(-cbA, bSI2, u);       \
        const float J2 = fmaf(-cgA, I2, I);         \
        const float I3 = fmaf(h2, bSI2, J2);        \
        float wb = fmaf(2.0f, bSI2, bSI1);          \
        float wI = fmaf(2.0f, I2, I);               \
        const float bSI3 = u3 * I3;                 \
        const float u4 = fmaf(-cbB, bSI3, u);       \
        const float J3 = fmaf(-cgB, I3, I);         \
        const float I4 = fmaf(h, bSI3, J3);         \
        wb = fmaf(2.0f, bSI3, wb);                  \
        wI = fmaf(2.0f, I3, wI);                    \
        const float bSI4 = u4 * I4;                 \
        wb += bSI4;                                 \
        wI += I4;                                   \
        u = fmaf(-cbF, wb, u);                      \
        const float tt = fmaf(-cgF, wI, I);         \
        I = fmaf(h6, wb, tt);                       \
    } while (0)

// advance one output step (i>0), per-step dt from the fp32 linspace chain
#define STEP(iexpr)                                                     \
    do {                                                                \
        const float tcur = step * (float)(iexpr);                       \
        const float dt   = tcur - tprev;                                \
        tprev = tcur;                                                   \
        const float h  = dt * (1.0f / SUB);                             \
        const float h2 = 0.5f * h;                                      \
        const float h6 = h * (1.0f / 6.0f);                             \
        const float cbA = h2 * beta,  cbB = h * beta,  cbF = h6 * beta; \
        const float cgA = h2 * gamma, cgB = h * gamma, cgF = h6 * gamma;\
        for (int s = 0; s < SUB; ++s) SUBSTEP();                        \
    } while (0)

// emit one 4-step group (12 floats) into this thread's LDS row, swizzled
#define EMIT_GROUP(Q4, IBASE)                                           \
    do {                                                                \
        float c[12];                                                    \
        _Pragma("unroll")                                               \
        for (int j = 0; j < 4; ++j) {                                   \
            const int i = (IBASE) + j;                                  \
            if (i > 0) STEP(i);                                         \
            const float Sout = bpos ? (u * rbeta) : S0;                 \
            c[j * 3 + 0] = Sout;                                        \
            c[j * 3 + 1] = I;                                           \
            c[j * 3 + 2] = 1.0f - Sout - I;                             \
        }                                                               \
        _Pragma("unroll")                                               \
        for (int cc = 0; cc < 3; ++cc) {                                \
            const int phys = ((Q4) * 3 + cc) ^ sw;                      \
            ldsrow4[phys] = make_float4(c[cc * 4], c[cc * 4 + 1],       \
                                        c[cc * 4 + 2], c[cc * 4 + 3]);  \
        }                                                               \
    } while (0)

__global__ __launch_bounds__(256, 1) void sir_rk4_dense_kernel(
    const float4* __restrict__ params, float* __restrict__ out)
{
    // 256 rows x 24 float4 chunks = 98304 B; wave w owns rows [w*64, w*64+64)
    __shared__ float4 lds4[256 * 24];

    const int tid  = threadIdx.x;
    const int lane = tid & 63;
    const int w    = tid >> 6;
    const int blk  = blockIdx.x;
    const int sw   = lane & 7;          // XOR bank swizzle key

    const float4 p = params[blk * 256 + tid];
    const float beta  = p.x;
    const float gamma = p.y;
    const float S0    = p.z;

    float u = beta * S0;                // rescaled state u = beta*S
    float I = p.w;

    const bool  bpos  = (beta > 0.0f);
    const float rbeta = bpos ? (1.0f / beta) : 0.0f;

    const float step = 100.0f / 199.0f; // fp32 linspace step
    float tprev = 0.0f;

    float4* ldsrow4 = lds4 + tid * 24;            // this thread's row
    const float4* ldsw4 = lds4 + (w * 64) * 24;   // wave slice base
    float4* out4 = reinterpret_cast<float4*>(out)
                 + (size_t)(blk * 256 + w * 64) * 150;  // 150 float4 per row

    // ---- 6 stages x 32 steps ----
    #pragma unroll 1
    for (int stage = 0; stage < 6; ++stage) {
        #pragma unroll 1
        for (int q4 = 0; q4 < 8; ++q4) {
            EMIT_GROUP(q4, stage * 32 + q4 * 4);
        }
        // wave-synchronous: all lanes' ds_writes visible before cross-lane reads
        asm volatile("s_waitcnt lgkmcnt(0)" ::: "memory");
        // dense drain, BATCHED: issue all 24 ds_reads back-to-back (one
        // latency instead of 24 serial ones), then 24 contiguous-run stores.
        // Stores have no waiters -> they drain under the next stage's compute.
        float4 dv[24];
        #pragma unroll
        for (int k = 0; k < 24; ++k) {
            const int id = k * 64 + lane;
            const int r  = id / 24;             // row within wave slice
            const int j  = id - r * 24;         // chunk within stage
            const int ph = j ^ (r & 7);
            dv[k] = ldsw4[r * 24 + ph];
        }
        #pragma unroll
        for (int k = 0; k < 24; ++k) {
            const int id = k * 64 + lane;
            const int r  = id / 24;
            const int j  = id - r * 24;
            out4[r * 150 + stage * 24 + j] = dv[k];
        }
    }

    // ---- tail stage: 8 steps (192..199) = 6 chunks/row ----
    {
        #pragma unroll 1
        for (int q4 = 0; q4 < 2; ++q4) {
            EMIT_GROUP(q4, 192 + q4 * 4);
        }
        asm volatile("s_waitcnt lgkmcnt(0)" ::: "memory");
        float4 dv[6];
        #pragma unroll
        for (int k = 0; k < 6; ++k) {
            const int id = k * 64 + lane;
            const int r  = id / 6;
            const int j  = id - r * 6;
            const int ph = j ^ (r & 7);
            dv[k] = ldsw4[r * 24 + ph];
        }
        #pragma unroll
        for (int k = 0; k < 6; ++k) {
            const int id = k * 64 + lane;
            const int r  = id / 6;
            const int j  = id - r * 6;
            out4[r * 150 + 144 + j] = dv[k];
        }
    }
}

extern "C" void kernel_launch(void* const* d_in, const int* in_sizes, int n_in,
                              void* d_out, int out_size, void* d_ws, size_t ws_size,
                              hipStream_t stream) {
    (void)in_sizes; (void)n_in; (void)out_size; (void)d_ws; (void)ws_size;
    const float4* params = (const float4*)d_in[0];
    float* out = (float*)d_out;
    sir_rk4_dense_kernel<<<NB / 256, 256, 0, stream>>>(params, out);
}